// Round 1
// 2740.926 us; speedup vs baseline: 1.0280x; 1.0280x over previous
//
#include <hip/hip_runtime.h>
#include <math.h>

#define TPB 1024   // 16 waves = 4/SIMD; thread = (freq = tid>>1, half = tid&1)
                   // PAIR LAYOUT: the two section-halves of a frequency are
                   // ADJACENT LANES -> L-exchange is one quad_perm DPP add,
                   // no Lpart LDS round-trip, no barrier #1 (3 -> 2 barriers/iter).

typedef float v2f __attribute__((ext_vector_type(2)));

// Compiler-generated packed math only — NO hand-written v_pk_* asm (R5/R7).
static __device__ __forceinline__ v2f fma2(v2f a, v2f b, v2f c) {
    return __builtin_elementwise_fma(a, b, c);
}
static __device__ __forceinline__ float rcp_nr(float x) {
    float r = __builtin_amdgcn_rcpf(x);
    return r * fmaf(-x, r, 2.0f);
}
// RAW v_rcp_f32 (~1 ulp): NR step dropped (R16). Perturbation absorbed like
// the R4/R8/R12 reorders (absmax 0.25, 16x under threshold, contracting).
static __device__ __forceinline__ v2f rcp2(v2f x) {
    v2f r;
    r.x = __builtin_amdgcn_rcpf(x.x);
    r.y = __builtin_amdgcn_rcpf(x.y);
    return r;
}

// Both lanes of an even/odd pair get the pair total (commutative add ->
// bit-identical K on both lanes). s_nop 1 covers VALU->DPP hazard.
static __device__ __forceinline__ float pair_sum(float L) {
    asm("s_nop 1\n\t"
        "v_add_f32 %0, %0, %0 quad_perm:[1,0,3,2] row_mask:0xf bank_mask:0xf bound_ctrl:0"
        : "+v"(L));
    return L;
}

// Six independent SINGLE stride-2 adds (halves interleave at stride 2, so one
// step reduces 2 same-half freqs): lanes (tid&3)>=2 hold valid partials.
// Half the DPP cost of the old 4-lane red6 (6 vs 12 adds/section).
__device__ __forceinline__ void red6_s2(float i0, float i1, float i2,
                                        float i3, float i4, float i5,
                                        float& o0, float& o1, float& o2,
                                        float& o3, float& o4, float& o5) {
    asm("s_nop 1\n\t"
        "v_add_f32 %0, %6, %6  row_shr:2 row_mask:0xf bank_mask:0xf bound_ctrl:0\n\t"
        "v_add_f32 %3, %9, %9  row_shr:2 row_mask:0xf bank_mask:0xf bound_ctrl:0\n\t"
        "v_add_f32 %1, %7, %7  row_shr:2 row_mask:0xf bank_mask:0xf bound_ctrl:0\n\t"
        "v_add_f32 %4, %10, %10 row_shr:2 row_mask:0xf bank_mask:0xf bound_ctrl:0\n\t"
        "v_add_f32 %2, %8, %8  row_shr:2 row_mask:0xf bank_mask:0xf bound_ctrl:0\n\t"
        "v_add_f32 %5, %11, %11 row_shr:2 row_mask:0xf bank_mask:0xf bound_ctrl:0"
        : "=&v"(o0), "=&v"(o1), "=&v"(o2), "=&v"(o3), "=&v"(o4), "=&v"(o5)
        : "v"(i0), "v"(i1), "v"(i2), "v"(i3), "v"(i4), "v"(i5));
}

// 8-lane combine for the update stage: lane (tid&7)==7 gets the group sum.
__device__ __forceinline__ float red1_g8(float g) {
    asm("s_nop 1\n\t"
        "v_add_f32 %0, %0, %0 row_shr:1 row_mask:0xf bank_mask:0xf bound_ctrl:0\n\t"
        "s_nop 1\n\t"
        "v_add_f32 %0, %0, %0 row_shr:2 row_mask:0xf bank_mask:0xf bound_ctrl:0\n\t"
        "s_nop 1\n\t"
        "v_add_f32 %0, %0, %0 row_shr:4 row_mask:0xf bank_mask:0xf bound_ctrl:0"
        : "+v"(g));
    return g;
}

// coefficient k (0..5 = b0,b1,b2,a0,a1,a2) -> paired column in
// [b0 a0 b1 a1 b2 a2]: b0,b1,b2 -> 0,2,4 ; a0,a1,a2 -> 1,3,5
__device__ __forceinline__ int cmap(int k) {
    return (k < 3) ? 2 * k : 2 * k - 5;
}

// GSTRIDE=132: 132*4=528 ≡ 0 mod 16 (float4 LDS ops must not split, R13);
// 132%32=4 -> 16 consecutive rows × float4 span spread evenly over all 32
// banks (pure-bandwidth 4-deep on stores, no wasted cycles).
#define GSTRIDE 132

__global__
__attribute__((amdgpu_flat_work_group_size(TPB, TPB), amdgpu_waves_per_eu(4, 4)))
void sgd_filter(const float* __restrict__ sos_in,
                const float* __restrict__ target,
                float* __restrict__ out) {
    // 16 sections x 6 floats, PAIRED, NO pad: [b0 a0 b1 a1 b2 a2].
    // 2 sections = 48 B -> 3 x 16B-aligned float4 per section pair.
    __shared__ __align__(16) float sos[96];
    // 256 rows (row = tid>>2 = 2 freqs per half), 16 sections x 8 cols
    // [b0 b1 b2 a0 a1 a2 pad pad]; half0 sections at cols 0..63, half1 64..127.
    __shared__ __align__(16) float gpart[256][GSTRIDE];

    const int tid  = threadIdx.x;
    const int fr   = tid >> 1;     // frequency (lane pairs share it)
    const int half = tid & 1;      // section half: 0 -> s0..7, 1 -> s8..15
    const float* secbase = &sos[half * 48];   // 8 sections x 6 floats

    if (tid < 96) sos[(tid / 6) * 6 + cmap(tid % 6)] = sos_in[tid];

    // Update identity: 8 threads per coefficient u = tid>>3 (tid<768; waves
    // 12..15 skip the whole update phase wave-uniformly).
    const int u    = tid >> 3;
    const int oct  = tid & 7;
    const int ucol = (u / 6) * 8 + (u % 6);       // gpart col (b0b1b2a0a1a2)
    const int uscol = (u / 6) * 6 + cmap(u % 6);  // sos col (paired layout)
    const bool upd = (tid < 768);
    const bool writer = upd && (oct == 7);
    float myc = 0.0f;
    if (writer) myc = sos_in[u];

    // Per-frequency constants
    const float w  = (float)((double)fr * (3.14159265358979323846 / 511.0));
    const float c1 = cosf(w);
    const float s1 = -sinf(w);           // z1 = e^{-jw}
    const float c2 = c1 * c1 - s1 * s1;  // z2 = z1^2
    const float s2 = 2.0f * c1 * s1;
    const float tgt = target[fr];
    const float KC = 40.0f / (512.0f * 2.302585092994046f); // 40/(n*ln10)

    v2f c1v; c1v.x = c1; c1v.y = c1;
    v2f s1v; s1v.x = s1; s1v.y = s1;
    v2f c2v; c2v.x = c2; c2v.y = c2;
    v2f s2v; s2v.x = s2; s2v.y = s2;

    __syncthreads();

    // 8 sections/thread: Re, Im, 1/n kept (1/n folded into K in backward ->
    // saves the tR/tI muls; 24 v2f = 48 VGPRs, still 4 waves/SIMD).
    v2f R0, R1, R2, R3, R4, R5, R6, R7;
    v2f I0, I1, I2, I3, I4, I5, I6, I7;
    v2f V0, V1, V2, V3, V4, V5, V6, V7;

// Two sections per 3 x ds_read_b128 (12 LDS reads/thread vs 16 padded).
#define SEC_PAIR(sa, sb)                                                     \
    {                                                                        \
        const float4 q0 = *(const float4*)(secbase + (sa) * 6);              \
        const float4 q1 = *(const float4*)(secbase + (sa) * 6 + 4);          \
        const float4 q2 = *(const float4*)(secbase + (sa) * 6 + 8);          \
        v2f ba0, ba1, ba2;                                                   \
        ba0.x = q0.x; ba0.y = q0.y;                                          \
        ba1.x = q0.z; ba1.y = q0.w;                                          \
        ba2.x = q1.x; ba2.y = q1.y;                                          \
        R##sa = fma2(ba2, c2v, fma2(ba1, c1v, ba0));                         \
        I##sa = fma2(ba2, s2v, ba1 * s1v);                                   \
        {                                                                    \
            const v2f n = fma2(R##sa, R##sa, I##sa * I##sa);                 \
            prod = prod * n;                                                 \
            V##sa = rcp2(n);                                                 \
        }                                                                    \
        ba0.x = q1.z; ba0.y = q1.w;                                          \
        ba1.x = q2.x; ba1.y = q2.y;                                          \
        ba2.x = q2.z; ba2.y = q2.w;                                          \
        R##sb = fma2(ba2, c2v, fma2(ba1, c1v, ba0));                         \
        I##sb = fma2(ba2, s2v, ba1 * s1v);                                   \
        {                                                                    \
            const v2f n = fma2(R##sb, R##sb, I##sb * I##sb);                 \
            prod = prod * n;                                                 \
            V##sb = rcp2(n);                                                 \
        }                                                                    \
    }

#define SEC_BWD(sl)                                                          \
    {                                                                        \
        const v2f KKs = KK * V##sl;           /* 1/n folded into K */        \
        const v2f P   = KKs * R##sl;          /* (g_b0, g_a0) */             \
        const v2f Q   = KKs * I##sl;                                         \
        const v2f G1  = fma2(c1v, P, s1v * Q); /* (g_b1, g_a1) */            \
        const v2f G2  = fma2(c2v, P, s2v * Q); /* (g_b2, g_a2) */            \
        float g0, g1, g2, g3, g4, g5;                                        \
        red6_s2(P.x, G1.x, G2.x, P.y, G1.y, G2.y,                            \
                g0, g1, g2, g3, g4, g5);                                     \
        if ((tid & 3) >= 2) {                                                \
            float* p = &gpart[tid >> 2][(sl) * 8 + 64 * half];               \
            *(float4*)p       = make_float4(g0, g1, g2, g3);                 \
            *(float2*)(p + 4) = make_float2(g4, g5);                         \
        }                                                                    \
    }

    for (int it = 0; it < 1000; ++it) {
        // ---- forward: partial L over my 8 sections (logs grouped 4x, same
        //      grouping as the verified kernel -> same over/underflow range)
        float L;
        v2f prod;
        prod.x = 1.0f; prod.y = 1.0f;
        SEC_PAIR(0, 1) SEC_PAIR(2, 3)
        L = __builtin_amdgcn_logf(prod.x) - __builtin_amdgcn_logf(prod.y);
        prod.x = 1.0f; prod.y = 1.0f;
        SEC_PAIR(4, 5) SEC_PAIR(6, 7)
        L += __builtin_amdgcn_logf(prod.x) - __builtin_amdgcn_logf(prod.y);

        // Pair exchange in-register: both lanes get the identical 16-section
        // total (add is commutative -> bit-identical K across the pair).
        const float Lt = pair_sum(L);

        const float mag   = __builtin_amdgcn_exp2f(0.5f * Lt);
        const float magpe = mag + 1e-8f;
        const float indB  = 6.020599913279624f * __builtin_amdgcn_logf(magpe);
        const float diff  = indB - tgt;
        const float K  = KC * diff * mag * rcp_nr(magpe);
        v2f KK; KK.x = K; KK.y = -K;     // A-side gradient sign folded here

        // ---- backward: scale directions, single-step DPP reduce, store ----
        SEC_BWD(0) SEC_BWD(1) SEC_BWD(2) SEC_BWD(3)
        SEC_BWD(4) SEC_BWD(5) SEC_BWD(6) SEC_BWD(7)
        __syncthreads();

        // ---- update: 8 threads/coeff, 32 rows each (2 chains for ILP),
        //      then 3-step DPP combine ----
        if (upd) {
            float a = 0.0f, b = 0.0f;
#pragma unroll
            for (int j = 0; j < 16; ++j) {
                a += gpart[16 * j + oct][ucol];
                b += gpart[16 * j + 8 + oct][ucol];
            }
            float g = red1_g8(a + b);
            if (writer) {
                myc = fmaf(-0.1f, g, myc);
                sos[uscol] = myc;
            }
        }
        __syncthreads();
    }

    if (writer) out[u] = myc;
}

extern "C" void kernel_launch(void* const* d_in, const int* in_sizes, int n_in,
                              void* d_out, int out_size, void* d_ws, size_t ws_size,
                              hipStream_t stream) {
    const float* sos_in = (const float*)d_in[0];
    const float* target = (const float*)d_in[1];
    float* outp = (float*)d_out;
    hipLaunchKernelGGL(sgd_filter, dim3(1), dim3(TPB), 0, stream, sos_in, target, outp);
}

// Round 2
// 2562.444 us; speedup vs baseline: 1.0996x; 1.0697x over previous
//
#include <hip/hip_runtime.h>
#include <math.h>

#define TPB 1024   // 16 waves = 4/SIMD; thread = (freq = tid>>1, half = tid&1)
                   // PAIR LAYOUT: the two section-halves of a frequency are
                   // ADJACENT LANES -> L-exchange is one quad_perm DPP add,
                   // no Lpart LDS round-trip (2 barriers/iter).

typedef float v2f __attribute__((ext_vector_type(2)));

// Compiler-generated packed math only — NO hand-written v_pk_* asm (R5/R7).
static __device__ __forceinline__ v2f fma2(v2f a, v2f b, v2f c) {
    return __builtin_elementwise_fma(a, b, c);
}
static __device__ __forceinline__ float rcp_nr(float x) {
    float r = __builtin_amdgcn_rcpf(x);
    return r * fmaf(-x, r, 2.0f);
}
// RAW v_rcp_f32 (~1 ulp): NR step dropped (R16). Perturbation absorbed like
// the R4/R8/R12 reorders (absmax stayed 8-16x under threshold, contracting).
static __device__ __forceinline__ v2f rcp2(v2f x) {
    v2f r;
    r.x = __builtin_amdgcn_rcpf(x.x);
    r.y = __builtin_amdgcn_rcpf(x.y);
    return r;
}

// Both lanes of an even/odd pair get the pair total (commutative add ->
// bit-identical K on both lanes). s_nop 1 covers VALU->DPP hazard.
static __device__ __forceinline__ float pair_sum(float L) {
    asm("s_nop 1\n\t"
        "v_add_f32 %0, %0, %0 quad_perm:[1,0,3,2] row_mask:0xf bank_mask:0xf bound_ctrl:0"
        : "+v"(L));
    return L;
}

// Six independent HALF-AWARE 4-freq reductions: stage 1 = stride-2 add
// (combines the 2 same-half freqs of a quad), stage 2 = stride-4 add
// (combines two quads). Lanes (tid&7)==6 (half0) and ==7 (half1) hold the
// 4-freq group sums. Round-robin gives 6-inst spacing; s_nop 1 covers the
// entry hazard (R0-verified pattern, strides changed for pair layout).
__device__ __forceinline__ void red6_g8(float i0, float i1, float i2,
                                        float i3, float i4, float i5,
                                        float& o0, float& o1, float& o2,
                                        float& o3, float& o4, float& o5) {
    asm("s_nop 1\n\t"
        "v_add_f32 %0, %6, %6  row_shr:2 row_mask:0xf bank_mask:0xf bound_ctrl:0\n\t"
        "v_add_f32 %3, %9, %9  row_shr:2 row_mask:0xf bank_mask:0xf bound_ctrl:0\n\t"
        "v_add_f32 %1, %7, %7  row_shr:2 row_mask:0xf bank_mask:0xf bound_ctrl:0\n\t"
        "v_add_f32 %4, %10, %10 row_shr:2 row_mask:0xf bank_mask:0xf bound_ctrl:0\n\t"
        "v_add_f32 %2, %8, %8  row_shr:2 row_mask:0xf bank_mask:0xf bound_ctrl:0\n\t"
        "v_add_f32 %5, %11, %11 row_shr:2 row_mask:0xf bank_mask:0xf bound_ctrl:0\n\t"
        "v_add_f32 %0, %0, %0 row_shr:4 row_mask:0xf bank_mask:0xf bound_ctrl:0\n\t"
        "v_add_f32 %3, %3, %3 row_shr:4 row_mask:0xf bank_mask:0xf bound_ctrl:0\n\t"
        "v_add_f32 %1, %1, %1 row_shr:4 row_mask:0xf bank_mask:0xf bound_ctrl:0\n\t"
        "v_add_f32 %4, %4, %4 row_shr:4 row_mask:0xf bank_mask:0xf bound_ctrl:0\n\t"
        "v_add_f32 %2, %2, %2 row_shr:4 row_mask:0xf bank_mask:0xf bound_ctrl:0\n\t"
        "v_add_f32 %5, %5, %5 row_shr:4 row_mask:0xf bank_mask:0xf bound_ctrl:0"
        : "=&v"(o0), "=&v"(o1), "=&v"(o2), "=&v"(o3), "=&v"(o4), "=&v"(o5)
        : "v"(i0), "v"(i1), "v"(i2), "v"(i3), "v"(i4), "v"(i5));
}

// 8-lane combine for the update stage: lane (tid&7)==7 gets the group sum.
__device__ __forceinline__ float red1_g8(float g) {
    asm("s_nop 1\n\t"
        "v_add_f32 %0, %0, %0 row_shr:1 row_mask:0xf bank_mask:0xf bound_ctrl:0\n\t"
        "s_nop 1\n\t"
        "v_add_f32 %0, %0, %0 row_shr:2 row_mask:0xf bank_mask:0xf bound_ctrl:0\n\t"
        "s_nop 1\n\t"
        "v_add_f32 %0, %0, %0 row_shr:4 row_mask:0xf bank_mask:0xf bound_ctrl:0"
        : "+v"(g));
    return g;
}

// coefficient k (0..5 = b0,b1,b2,a0,a1,a2) -> paired column in
// [b0 a0 b1 a1 b2 a2]: b0,b1,b2 -> 0,2,4 ; a0,a1,a2 -> 1,3,5
__device__ __forceinline__ int cmap(int k) {
    return (k < 3) ? 2 * k : 2 * k - 5;
}

// gpart column layout, BANK-BALANCED (R2): section sec gets 8 cols at
// (sec&7)*8 + 64*(sec>>3); within the block, coefficient k sits at column
// ck[sec&3][k] chosen so every wave of 8 consecutive coefficients has its
// 8 column residues mod 4 exactly balanced 2-2-2-2 -> update reads are
// provably 2 lanes/bank (free, m136). Types:
//   sec&3 == 0,2 : {0,1,2,3,6,7}
//   sec&3 == 1   : {0,1,4,5,6,7}
//   sec&3 == 3   : {0,1,2,3,4,5}
__device__ __forceinline__ int ckmap(int ty, int k) {
    return (ty == 3) ? k : ((ty == 1) ? (k < 2 ? k : k + 2)
                                      : (k < 4 ? k : k + 2));
}

// GSTRIDE=132: 132*4=528 ≡ 0 mod 16 (float4 LDS ops must not split, R13);
// 132%32=4 -> writer rows spread 8 start-banks, 2 starts/bank (free).
#define GSTRIDE 132

__global__
__attribute__((amdgpu_flat_work_group_size(TPB, TPB), amdgpu_waves_per_eu(4, 4)))
void sgd_filter(const float* __restrict__ sos_in,
                const float* __restrict__ target,
                float* __restrict__ out) {
    // 16 sections x 6 floats, PAIRED, NO pad: [b0 a0 b1 a1 b2 a2].
    __shared__ __align__(16) float sos[96];
    // 128 rows (row = tid>>3 = one 4-freq group), 16 sections x 8 cols;
    // half0 sections at cols 0..63, half1 at 64..127 (type-mapped inside).
    __shared__ __align__(16) float gpart[128][GSTRIDE];

    const int tid  = threadIdx.x;
    const int fr   = tid >> 1;     // frequency (lane pairs share it)
    const int half = tid & 1;      // section half: 0 -> s0..7, 1 -> s8..15
    const float* secbase = &sos[half * 48];   // 8 sections x 6 floats

    if (tid < 96) sos[(tid / 6) * 6 + cmap(tid % 6)] = sos_in[tid];

    // Update identity: 8 threads per coefficient u = tid>>3 (tid<768; waves
    // 12..15 skip the whole update phase wave-uniformly).
    const int u    = tid >> 3;
    const int oct  = tid & 7;
    const int usec = u / 6;
    const int uk   = u % 6;
    const int ucol = (usec & 7) * 8 + 64 * (usec >> 3) + ckmap(usec & 3, uk);
    const int uscol = usec * 6 + cmap(uk);        // sos col (paired layout)
    const bool upd = (tid < 768);
    const bool writer = upd && (oct == 7);
    float myc = 0.0f;
    if (writer) myc = sos_in[u];

    // Per-frequency constants
    const float w  = (float)((double)fr * (3.14159265358979323846 / 511.0));
    const float c1 = cosf(w);
    const float s1 = -sinf(w);           // z1 = e^{-jw}
    const float c2 = c1 * c1 - s1 * s1;  // z2 = z1^2
    const float s2 = 2.0f * c1 * s1;
    const float tgt = target[fr];
    const float KC = 40.0f / (512.0f * 2.302585092994046f); // 40/(n*ln10)

    v2f c1v; c1v.x = c1; c1v.y = c1;
    v2f s1v; s1v.x = s1; s1v.y = s1;
    v2f c2v; c2v.x = c2; c2v.y = c2;
    v2f s2v; s2v.x = s2; s2v.y = s2;

    __syncthreads();

    // 8 sections/thread: Re, Im, 1/n kept (1/n folded into K in backward ->
    // saves the tR/tI muls; 24 v2f = 48 VGPRs, still 4 waves/SIMD).
    v2f R0, R1, R2, R3, R4, R5, R6, R7;
    v2f I0, I1, I2, I3, I4, I5, I6, I7;
    v2f V0, V1, V2, V3, V4, V5, V6, V7;

// Two sections per 3 x ds_read_b128 (12 LDS reads/thread vs 16 padded);
// all lanes of a half read the SAME address -> broadcast, conflict-free.
#define SEC_PAIR(sa, sb)                                                     \
    {                                                                        \
        const float4 q0 = *(const float4*)(secbase + (sa) * 6);              \
        const float4 q1 = *(const float4*)(secbase + (sa) * 6 + 4);          \
        const float4 q2 = *(const float4*)(secbase + (sa) * 6 + 8);          \
        v2f ba0, ba1, ba2;                                                   \
        ba0.x = q0.x; ba0.y = q0.y;                                          \
        ba1.x = q0.z; ba1.y = q0.w;                                          \
        ba2.x = q1.x; ba2.y = q1.y;                                          \
        R##sa = fma2(ba2, c2v, fma2(ba1, c1v, ba0));                         \
        I##sa = fma2(ba2, s2v, ba1 * s1v);                                   \
        {                                                                    \
            const v2f n = fma2(R##sa, R##sa, I##sa * I##sa);                 \
            prod = prod * n;                                                 \
            V##sa = rcp2(n);                                                 \
        }                                                                    \
        ba0.x = q1.z; ba0.y = q1.w;                                          \
        ba1.x = q2.x; ba1.y = q2.y;                                          \
        ba2.x = q2.z; ba2.y = q2.w;                                          \
        R##sb = fma2(ba2, c2v, fma2(ba1, c1v, ba0));                         \
        I##sb = fma2(ba2, s2v, ba1 * s1v);                                   \
        {                                                                    \
            const v2f n = fma2(R##sb, R##sb, I##sb * I##sb);                 \
            prod = prod * n;                                                 \
            V##sb = rcp2(n);                                                 \
        }                                                                    \
    }

// Backward: scale stored directions, 2-stage DPP reduce (4 freqs/group),
// writers = lanes (tid&7)==6 (half0) / ==7 (half1), 16 lanes/wave ->
// 2 float4-starts per bank = free. Column placement follows ckmap(sl&3,·):
//   ty 0,2: cols {0,1,2,3,6,7} -> f4@0,  f2@6
//   ty 1  : cols {0,1,4,5,6,7} -> f2@0,  f4@4
//   ty 3  : cols {0,1,2,3,4,5} -> f4@0,  f2@4
#define SEC_BWD(sl)                                                          \
    {                                                                        \
        const v2f KKs = KK * V##sl;           /* 1/n folded into K */        \
        const v2f P   = KKs * R##sl;          /* (g_b0, g_a0) */             \
        const v2f Q   = KKs * I##sl;                                         \
        const v2f G1  = fma2(c1v, P, s1v * Q); /* (g_b1, g_a1) */            \
        const v2f G2  = fma2(c2v, P, s2v * Q); /* (g_b2, g_a2) */            \
        float g0, g1, g2, g3, g4, g5;                                        \
        red6_g8(P.x, G1.x, G2.x, P.y, G1.y, G2.y,                            \
                g0, g1, g2, g3, g4, g5);                                     \
        if ((tid & 7) >= 6) {                                                \
            float* p = &gpart[tid >> 3][(sl) * 8 + 64 * half];               \
            if (((sl) & 3) == 1) {                                           \
                *(float2*)p       = make_float2(g0, g1);                     \
                *(float4*)(p + 4) = make_float4(g2, g3, g4, g5);             \
            } else if (((sl) & 3) == 3) {                                    \
                *(float4*)p       = make_float4(g0, g1, g2, g3);             \
                *(float2*)(p + 4) = make_float2(g4, g5);                     \
            } else {                                                         \
                *(float4*)p       = make_float4(g0, g1, g2, g3);             \
                *(float2*)(p + 6) = make_float2(g4, g5);                     \
            }                                                                \
        }                                                                    \
    }

    for (int it = 0; it < 1000; ++it) {
        // ---- forward: partial L over my 8 sections (logs grouped 4x) ----
        float L;
        v2f prod;
        prod.x = 1.0f; prod.y = 1.0f;
        SEC_PAIR(0, 1) SEC_PAIR(2, 3)
        L = __builtin_amdgcn_logf(prod.x) - __builtin_amdgcn_logf(prod.y);
        prod.x = 1.0f; prod.y = 1.0f;
        SEC_PAIR(4, 5) SEC_PAIR(6, 7)
        L += __builtin_amdgcn_logf(prod.x) - __builtin_amdgcn_logf(prod.y);

        // Pair exchange in-register: both lanes get the identical 16-section
        // total (add is commutative -> bit-identical K across the pair).
        const float Lt = pair_sum(L);

        const float mag   = __builtin_amdgcn_exp2f(0.5f * Lt);
        const float magpe = mag + 1e-8f;
        const float indB  = 6.020599913279624f * __builtin_amdgcn_logf(magpe);
        const float diff  = indB - tgt;
        const float K  = KC * diff * mag * rcp_nr(magpe);
        v2f KK; KK.x = K; KK.y = -K;     // A-side gradient sign folded here

        // ---- backward: scale directions, 2-stage DPP reduce, store ----
        SEC_BWD(0) SEC_BWD(1) SEC_BWD(2) SEC_BWD(3)
        SEC_BWD(4) SEC_BWD(5) SEC_BWD(6) SEC_BWD(7)
        __syncthreads();

        // ---- update: 8 threads/coeff, 16 rows each (2 chains for ILP),
        //      bank-balanced cols -> 2-way reads (free), then 3-step DPP ----
        if (upd) {
            float a = 0.0f, b = 0.0f;
#pragma unroll
            for (int j = 0; j < 8; ++j) {
                a += gpart[8 * j + oct][ucol];
                b += gpart[8 * (j + 8) + oct][ucol];
            }
            float g = red1_g8(a + b);
            if (writer) {
                myc = fmaf(-0.1f, g, myc);
                sos[uscol] = myc;
            }
        }
        __syncthreads();
    }

    if (writer) out[u] = myc;
}

extern "C" void kernel_launch(void* const* d_in, const int* in_sizes, int n_in,
                              void* d_out, int out_size, void* d_ws, size_t ws_size,
                              hipStream_t stream) {
    const float* sos_in = (const float*)d_in[0];
    const float* target = (const float*)d_in[1];
    float* outp = (float*)d_out;
    hipLaunchKernelGGL(sgd_filter, dim3(1), dim3(TPB), 0, stream, sos_in, target, outp);
}